// Round 10
// baseline (130.579 us; speedup 1.0000x reference)
//
#include <hip/hip_runtime.h>
#include <math.h>

#define BB 32
#define CC 256
#define HH 64
#define WW 64
#define RR 16
#define HWSZ (HH * WW)          // 4096
#define POS 205                 // max(1, round(0.8 * 256))

typedef float f32x4 __attribute__((ext_vector_type(4)));

// ws layout (element offsets, 4B units):
//   y        : [0, 8192)        per-(b,c) means
//   batch_cnt: [8192, 8224)     u32 arrival counters (memset to 0 each launch)
//   mcnt     : [8224, 8256)     per-batch masked-channel count
//   mlist    : [8256, 8256+32*52)  per-batch masked channel ids
#define WS_Y     0
#define WS_BCNT  8192
#define WS_MCNT  8224
#define WS_MLIST 8256

// ---------------------------------------------------------------------------
// Kernel 1: fused copy + mean + (per-batch last-finisher) SE mask.
// 2048 blocks x 256 threads; block handles 4 rows (all in batch blk>>6).
// batch_cnt is zeroed by hipMemsetAsync each launch, so (old==63) identifies
// the TRUE 64th (last) arrival per batch. The finisher re-reads peer-written
// y via device-scope atomic loads (per-XCD L2 is not coherent for plain
// loads), then computes the SE bottleneck + rank mask and emits a compacted
// masked-channel list. SE overlaps with other batches' ongoing copies.
// ---------------------------------------------------------------------------
__global__ void mean_copy_se_kernel(const float* __restrict__ x,
                                    const float* __restrict__ W1,
                                    const float* __restrict__ W2,
                                    float* __restrict__ out,
                                    float* __restrict__ ws) {
    const int blk = blockIdx.x;                  // 0..2047
    const int t = threadIdx.x;                   // 0..255
    const int r0 = blk * 4;                      // rows r0..r0+3 (same batch)
    const int b = blk >> 6;                      // batch 0..31

    float* y = ws + WS_Y;
    unsigned int* batch_cnt = (unsigned int*)(ws + WS_BCNT);
    int* mcnt  = (int*)(ws + WS_MCNT);
    int* mlist = (int*)(ws + WS_MLIST);

    __shared__ float red[8];
    const int wave = t >> 6;
    const int lane = t & 63;

    // ---- copy + mean, two row-pairs (8 x 16B loads in flight per pair) ----
#pragma unroll
    for (int p = 0; p < 2; ++p) {
        const int rA = r0 + 2 * p;
        const f32x4* xA = (const f32x4*)(x + (size_t)rA * HWSZ);
        f32x4* oA = (f32x4*)(out + (size_t)rA * HWSZ);

        f32x4 v0[4], v1[4];
#pragma unroll
        for (int i = 0; i < 4; ++i) v0[i] = xA[t + i * 256];
#pragma unroll
        for (int i = 0; i < 4; ++i) v1[i] = xA[1024 + t + i * 256];

        float s0 = 0.f, s1 = 0.f;
#pragma unroll
        for (int i = 0; i < 4; ++i) {
            __builtin_nontemporal_store(v0[i], &oA[t + i * 256]);
            s0 += v0[i].x + v0[i].y + v0[i].z + v0[i].w;
        }
#pragma unroll
        for (int i = 0; i < 4; ++i) {
            __builtin_nontemporal_store(v1[i], &oA[1024 + t + i * 256]);
            s1 += v1[i].x + v1[i].y + v1[i].z + v1[i].w;
        }
#pragma unroll
        for (int off = 32; off > 0; off >>= 1) {
            s0 += __shfl_down(s0, off, 64);
            s1 += __shfl_down(s1, off, 64);
        }
        if (lane == 0) { red[wave] = s0; red[wave + 4] = s1; }
        __syncthreads();
        if (t == 0) {
            y[rA]     = (red[0] + red[1] + red[2] + red[3]) * (1.0f / (float)HWSZ);
            y[rA + 1] = (red[4] + red[5] + red[6] + red[7]) * (1.0f / (float)HWSZ);
        }
        __syncthreads();                         // red[] reuse protection
    }

    // ---- arrival; TRUE 64th block per batch becomes the SE finisher ----
    __shared__ int fin;
    if (t == 0) {
        __threadfence();                          // release y writes
        unsigned int old = atomicAdd(&batch_cnt[b], 1u);
        fin = (old == 63u) ? 1 : 0;               // counter reset each launch
    }
    __syncthreads();
    if (!fin) return;

    // ---- SE bottleneck + rank mask for batch b (finisher block only) ----
    __shared__ float ys[CC];
    __shared__ float hs[RR];
    __shared__ float ss[CC];
    __shared__ int woff[4];

    // device-scope coherent read of peer-written y (atomicAdd(.,0) = atomic load)
    ys[t] = atomicAdd(&y[b * CC + t], 0.0f);
    __syncthreads();

    {   // h[r]: r = t>>4 (0..15), 16-lane group splits the 256-dot
        const int r = t >> 4;
        const int p = t & 15;
        float acc = 0.f;
#pragma unroll
        for (int j = 0; j < 16; ++j)
            acc += ys[p * 16 + j] * W1[r * CC + p * 16 + j];
#pragma unroll
        for (int off = 8; off > 0; off >>= 1) acc += __shfl_xor(acc, off, 16);
        if (p == 0) hs[r] = fmaxf(acc, 0.f);
    }
    __syncthreads();

    float acc = 0.f;
#pragma unroll
    for (int r = 0; r < RR; ++r) acc += hs[r] * W2[t * RR + r];
    const float s = 1.0f / (1.0f + expf(-acc));
    ss[t] = s;
    __syncthreads();

    int cnt = 0;
    for (int j = 0; j < CC; ++j) cnt += (ss[j] < s) ? 1 : 0;
    const int masked = (cnt <= POS - 1) ? 0 : 1;  // masked = NOT kept

    // ---- ballot-compact masked channel list ----
    unsigned long long mm = __ballot(masked);
    if (lane == 0) woff[wave] = __popcll(mm);
    __syncthreads();
    int off = 0;
#pragma unroll
    for (int wv = 0; wv < 4; ++wv) if (wv < wave) off += woff[wv];
    if (masked) {
        int idx = off + __popcll(mm & ((1ull << lane) - 1ull));
        mlist[b * 52 + idx] = t;                  // channel id
    }
    if (t == 0) mcnt[b] = woff[0] + woff[1] + woff[2] + woff[3];
}

// ---------------------------------------------------------------------------
// Kernel 2: zero listed masked rows. 32*51 = 1632 blocks; block i of batch b
// zeroes mlist[b][i] if i < mcnt[b]. Pure ~27 MB NT write burst.
// (Kernel boundary = full barrier + cache flush, so mcnt/mlist are safe.)
// ---------------------------------------------------------------------------
__global__ void zero_kernel(const float* __restrict__ ws,
                            float* __restrict__ out) {
    const int blk = blockIdx.x;
    const int b = blk / 51;
    const int i = blk % 51;
    const int* mcnt  = (const int*)(ws + WS_MCNT);
    const int* mlist = (const int*)(ws + WS_MLIST);
    if (i >= mcnt[b]) return;
    const int c = mlist[b * 52 + i];
    const int t = threadIdx.x;
    f32x4* orow = (f32x4*)(out + ((size_t)b * CC + c) * HWSZ);
    f32x4 z = {0.f, 0.f, 0.f, 0.f};
#pragma unroll
    for (int k = 0; k < 4; ++k)
        __builtin_nontemporal_store(z, &orow[t + k * 256]);
}

extern "C" void kernel_launch(void* const* d_in, const int* in_sizes, int n_in,
                              void* d_out, int out_size, void* d_ws, size_t ws_size,
                              hipStream_t stream) {
    const float* x  = (const float*)d_in[0];
    const float* W1 = (const float*)d_in[1];
    const float* W2 = (const float*)d_in[2];
    float* out = (float*)d_out;
    float* ws = (float*)d_ws;

    // zero the 32 arrival counters every launch (async, graph-capture-safe)
    hipMemsetAsync((char*)d_ws + WS_BCNT * 4, 0, 32 * 4, stream);

    mean_copy_se_kernel<<<2048, 256, 0, stream>>>(x, W1, W2, out, ws);
    zero_kernel<<<BB * 51, 256, 0, stream>>>(ws, out);
}

// Round 11
// 61.851 us; speedup vs baseline: 2.1112x; 2.1112x over previous
//
#include <hip/hip_runtime.h>
#include <math.h>

#define BB 32
#define CC 256
#define HH 64
#define WW 64
#define RR 16
#define HWSZ (HH * WW)          // 4096
#define POS 205                 // max(1, round(0.8 * 256))

typedef float f32x4 __attribute__((ext_vector_type(4)));

// ws layout (element offsets, 4B units):
//   y        : [0, 8192)        per-(b,c) means (written via atomicExch)
//   batch_cnt: [8192, 8224)     u32 arrival counters (memset to 0 each launch)
//   mcnt     : [8224, 8256)     per-batch masked-channel count
//   mlist    : [8256, 8256+32*52)  per-batch masked channel ids
#define WS_Y     0
#define WS_BCNT  8192
#define WS_MCNT  8224
#define WS_MLIST 8256

// ---------------------------------------------------------------------------
// Kernel 1: fused copy + mean + per-batch last-finisher SE mask.
// 2048 blocks x 256 threads; block handles 4 rows (batch = blk>>6).
// Coherence WITHOUT fences (R10's per-block __threadfence lowered to L2
// writebacks and cost 150us): y means are PUBLISHED with device-scope
// atomicExch (executes at the LLC coherence point, cross-XCD coherent),
// ordered before the arrival-counter bump by a plain s_waitcnt vmcnt(0)
// (waits for this wave's y atomics to complete; no cache flush). The true
// 64th arrival per batch reads peers' y with atomic loads and computes the
// SE bottleneck + rank mask, emitting a compacted masked-channel list.
// ---------------------------------------------------------------------------
__global__ void mean_copy_se_kernel(const float* __restrict__ x,
                                    const float* __restrict__ W1,
                                    const float* __restrict__ W2,
                                    float* __restrict__ out,
                                    float* __restrict__ ws) {
    const int blk = blockIdx.x;                  // 0..2047
    const int t = threadIdx.x;                   // 0..255
    const int r0 = blk * 4;                      // rows r0..r0+3 (same batch)
    const int b = blk >> 6;                      // batch 0..31

    float* y = ws + WS_Y;
    unsigned int* batch_cnt = (unsigned int*)(ws + WS_BCNT);
    int* mcnt  = (int*)(ws + WS_MCNT);
    int* mlist = (int*)(ws + WS_MLIST);

    __shared__ float red[8];
    const int wave = t >> 6;
    const int lane = t & 63;

    // ---- copy + mean, two row-pairs (8 x 16B loads in flight per pair) ----
#pragma unroll
    for (int p = 0; p < 2; ++p) {
        const int rA = r0 + 2 * p;
        const f32x4* xA = (const f32x4*)(x + (size_t)rA * HWSZ);
        f32x4* oA = (f32x4*)(out + (size_t)rA * HWSZ);

        f32x4 v0[4], v1[4];
#pragma unroll
        for (int i = 0; i < 4; ++i) v0[i] = xA[t + i * 256];
#pragma unroll
        for (int i = 0; i < 4; ++i) v1[i] = xA[1024 + t + i * 256];

        float s0 = 0.f, s1 = 0.f;
#pragma unroll
        for (int i = 0; i < 4; ++i) {
            __builtin_nontemporal_store(v0[i], &oA[t + i * 256]);
            s0 += v0[i].x + v0[i].y + v0[i].z + v0[i].w;
        }
#pragma unroll
        for (int i = 0; i < 4; ++i) {
            __builtin_nontemporal_store(v1[i], &oA[1024 + t + i * 256]);
            s1 += v1[i].x + v1[i].y + v1[i].z + v1[i].w;
        }
#pragma unroll
        for (int off = 32; off > 0; off >>= 1) {
            s0 += __shfl_down(s0, off, 64);
            s1 += __shfl_down(s1, off, 64);
        }
        if (lane == 0) { red[wave] = s0; red[wave + 4] = s1; }
        __syncthreads();
        if (t == 0) {
            // publish means at the coherence point (cross-XCD coherent, no fence)
            atomicExch(&y[rA],     (red[0] + red[1] + red[2] + red[3]) * (1.0f / (float)HWSZ));
            atomicExch(&y[rA + 1], (red[4] + red[5] + red[6] + red[7]) * (1.0f / (float)HWSZ));
        }
        __syncthreads();                         // red[] reuse protection
    }

    // ---- arrival; TRUE 64th block per batch becomes the SE finisher ----
    __shared__ int fin;
    if (t == 0) {
        // order: y atomics must complete (reach LLC) before the counter bump
        asm volatile("s_waitcnt vmcnt(0)" ::: "memory");
        unsigned int old = atomicAdd(&batch_cnt[b], 1u);
        fin = (old == 63u) ? 1 : 0;               // counters zeroed each launch
    }
    __syncthreads();
    if (!fin) return;

    // ---- SE bottleneck + rank mask for batch b (finisher block only) ----
    __shared__ float ys[CC];
    __shared__ float hs[RR];
    __shared__ float ss[CC];
    __shared__ int woff[4];

    // coherent atomic load of peer-written y
    ys[t] = atomicAdd(&y[b * CC + t], 0.0f);
    __syncthreads();

    {   // h[r]: r = t>>4 (0..15), 16-lane group splits the 256-dot
        const int r = t >> 4;
        const int p = t & 15;
        float acc = 0.f;
#pragma unroll
        for (int j = 0; j < 16; ++j)
            acc += ys[p * 16 + j] * W1[r * CC + p * 16 + j];
#pragma unroll
        for (int off = 8; off > 0; off >>= 1) acc += __shfl_xor(acc, off, 16);
        if (p == 0) hs[r] = fmaxf(acc, 0.f);
    }
    __syncthreads();

    float acc = 0.f;
#pragma unroll
    for (int r = 0; r < RR; ++r) acc += hs[r] * W2[t * RR + r];
    const float s = 1.0f / (1.0f + expf(-acc));
    ss[t] = s;
    __syncthreads();

    int cnt = 0;
    for (int j = 0; j < CC; ++j) cnt += (ss[j] < s) ? 1 : 0;
    const int masked = (cnt <= POS - 1) ? 0 : 1;  // masked = NOT kept

    // ---- ballot-compact masked channel list ----
    unsigned long long mm = __ballot(masked);
    if (lane == 0) woff[wave] = __popcll(mm);
    __syncthreads();
    int off = 0;
#pragma unroll
    for (int wv = 0; wv < 4; ++wv) if (wv < wave) off += woff[wv];
    if (masked) {
        int idx = off + __popcll(mm & ((1ull << lane) - 1ull));
        mlist[b * 52 + idx] = t;                  // channel id
    }
    if (t == 0) mcnt[b] = woff[0] + woff[1] + woff[2] + woff[3];
}

// ---------------------------------------------------------------------------
// Kernel 2: zero listed masked rows. 32*51 = 1632 blocks; block i of batch b
// zeroes mlist[b][i] if i < mcnt[b]. Pure ~27 MB NT write burst.
// (Kernel boundary provides the release/acquire for mcnt/mlist.)
// ---------------------------------------------------------------------------
__global__ void zero_kernel(const float* __restrict__ ws,
                            float* __restrict__ out) {
    const int blk = blockIdx.x;
    const int b = blk / 51;
    const int i = blk % 51;
    const int* mcnt  = (const int*)(ws + WS_MCNT);
    const int* mlist = (const int*)(ws + WS_MLIST);
    if (i >= mcnt[b]) return;
    const int c = mlist[b * 52 + i];
    const int t = threadIdx.x;
    f32x4* orow = (f32x4*)(out + ((size_t)b * CC + c) * HWSZ);
    f32x4 z = {0.f, 0.f, 0.f, 0.f};
#pragma unroll
    for (int k = 0; k < 4; ++k)
        __builtin_nontemporal_store(z, &orow[t + k * 256]);
}

extern "C" void kernel_launch(void* const* d_in, const int* in_sizes, int n_in,
                              void* d_out, int out_size, void* d_ws, size_t ws_size,
                              hipStream_t stream) {
    const float* x  = (const float*)d_in[0];
    const float* W1 = (const float*)d_in[1];
    const float* W2 = (const float*)d_in[2];
    float* out = (float*)d_out;
    float* ws = (float*)d_ws;

    // zero the 32 arrival counters every launch (async, graph-capture-safe)
    hipMemsetAsync((char*)d_ws + WS_BCNT * 4, 0, 32 * 4, stream);

    mean_copy_se_kernel<<<2048, 256, 0, stream>>>(x, W1, W2, out, ws);
    zero_kernel<<<BB * 51, 256, 0, stream>>>(ws, out);
}

// Round 12
// 54.147 us; speedup vs baseline: 2.4116x; 1.1423x over previous
//
#include <hip/hip_runtime.h>
#include <math.h>

#define BB 32
#define CC 256
#define HH 64
#define WW 64
#define RR 16
#define HWSZ (HH * WW)          // 4096
#define POS 205                 // max(1, round(0.8 * 256))

typedef float f32x4 __attribute__((ext_vector_type(4)));

// ---------------------------------------------------------------------------
// Kernel 1: fused copy + mean, 4 rows per block (2048 blocks).
// Plain caching loads; NT stores (keep out from evicting x in LLC).
// Two row-pairs; each pair has 8 x 16B loads in flight per thread.
// y written with plain stores — kernel boundary publishes them for K2.
// ---------------------------------------------------------------------------
__global__ void mean_copy_kernel(const float* __restrict__ x,
                                 float* __restrict__ out,
                                 float* __restrict__ y) {
    const int blk = blockIdx.x;                  // 0..2047
    const int t = threadIdx.x;                   // 0..255
    const int r0 = blk * 4;                      // rows r0..r0+3

    __shared__ float red[8];
    const int wave = t >> 6;
    const int lane = t & 63;

#pragma unroll
    for (int p = 0; p < 2; ++p) {
        const int rA = r0 + 2 * p;
        const f32x4* xA = (const f32x4*)(x + (size_t)rA * HWSZ);
        f32x4* oA = (f32x4*)(out + (size_t)rA * HWSZ);

        f32x4 v0[4], v1[4];
#pragma unroll
        for (int i = 0; i < 4; ++i) v0[i] = xA[t + i * 256];
#pragma unroll
        for (int i = 0; i < 4; ++i) v1[i] = xA[1024 + t + i * 256];

        float s0 = 0.f, s1 = 0.f;
#pragma unroll
        for (int i = 0; i < 4; ++i) {
            __builtin_nontemporal_store(v0[i], &oA[t + i * 256]);
            s0 += v0[i].x + v0[i].y + v0[i].z + v0[i].w;
        }
#pragma unroll
        for (int i = 0; i < 4; ++i) {
            __builtin_nontemporal_store(v1[i], &oA[1024 + t + i * 256]);
            s1 += v1[i].x + v1[i].y + v1[i].z + v1[i].w;
        }
#pragma unroll
        for (int off = 32; off > 0; off >>= 1) {
            s0 += __shfl_down(s0, off, 64);
            s1 += __shfl_down(s1, off, 64);
        }
        if (lane == 0) { red[wave] = s0; red[wave + 4] = s1; }
        __syncthreads();
        if (t == 0) {
            y[rA]     = (red[0] + red[1] + red[2] + red[3]) * (1.0f / (float)HWSZ);
            y[rA + 1] = (red[4] + red[5] + red[6] + red[7]) * (1.0f / (float)HWSZ);
        }
        __syncthreads();                         // red[] reuse protection
    }
}

// ---------------------------------------------------------------------------
// Kernel 2: fused SE + zero, 2048 blocks = 64 per batch (R8-proven).
// Ballot-based rank count for the block's own 4 channels only, then zero
// masked channels {k, k+64, k+128, k+192} of batch b with NT writes.
// ---------------------------------------------------------------------------
__global__ void se_zero_kernel(const float* __restrict__ y,
                               const float* __restrict__ W1,
                               const float* __restrict__ W2,
                               float* __restrict__ out) {
    const int b = blockIdx.x >> 6;                   // batch 0..31
    const int k = blockIdx.x & 63;                   // sub-block 0..63
    const int t = threadIdx.x;                       // 0 .. 255
    __shared__ float ys[CC];
    __shared__ float hs[RR];
    __shared__ float ss[CC];
    __shared__ int cntred[4][4];                     // [cc][wave]
    __shared__ int keepb[4];

    ys[t] = y[b * CC + t];
    __syncthreads();

    {   // h[r]: r = t>>4 (0..15), 16-lane group splits the 256-dot
        const int r = t >> 4;
        const int p = t & 15;
        float acc = 0.f;
#pragma unroll
        for (int j = 0; j < 16; ++j)
            acc += ys[p * 16 + j] * W1[r * CC + p * 16 + j];
#pragma unroll
        for (int off = 8; off > 0; off >>= 1) acc += __shfl_xor(acc, off, 16);
        if (p == 0) hs[r] = fmaxf(acc, 0.f);
    }
    __syncthreads();

    float acc = 0.f;
#pragma unroll
    for (int r = 0; r < RR; ++r) acc += hs[r] * W2[t * RR + r];
    const float s = 1.0f / (1.0f + expf(-acc));
    ss[t] = s;
    __syncthreads();

    // rank counts for this block's 4 channels only, via wave ballots
    const int wave = t >> 6;
#pragma unroll
    for (int cc = 0; cc < 4; ++cc) {
        const float sc = ss[k + cc * 64];
        unsigned long long m = __ballot(s < sc);     // lanes j with s[j] < s[c]
        if ((t & 63) == 0) cntred[cc][wave] = __popcll(m);
    }
    __syncthreads();
    if (t < 4)
        keepb[t] = (cntred[t][0] + cntred[t][1] + cntred[t][2] + cntred[t][3]) <= POS - 1;
    __syncthreads();

    // zero phase: channels {k, k+64, k+128, k+192} of batch b
    f32x4 z = {0.f, 0.f, 0.f, 0.f};
#pragma unroll
    for (int cc = 0; cc < 4; ++cc) {
        if (keepb[cc]) continue;
        const int c = k + cc * 64;
        f32x4* orow = (f32x4*)(out + ((size_t)b * CC + c) * HWSZ);
#pragma unroll
        for (int i = 0; i < 4; ++i)
            __builtin_nontemporal_store(z, &orow[t + i * 256]);
    }
}

extern "C" void kernel_launch(void* const* d_in, const int* in_sizes, int n_in,
                              void* d_out, int out_size, void* d_ws, size_t ws_size,
                              hipStream_t stream) {
    const float* x  = (const float*)d_in[0];
    const float* W1 = (const float*)d_in[1];
    const float* W2 = (const float*)d_in[2];
    float* out = (float*)d_out;

    float* y = (float*)d_ws;                    // B*C floats

    mean_copy_kernel<<<2048, 256, 0, stream>>>(x, out, y);
    se_zero_kernel<<<BB * 64, 256, 0, stream>>>(y, W1, W2, out);
}

// Round 13
// 53.913 us; speedup vs baseline: 2.4220x; 1.0043x over previous
//
#include <hip/hip_runtime.h>
#include <math.h>

#define BB 32
#define CC 256
#define HH 64
#define WW 64
#define RR 16
#define HWSZ (HH * WW)          // 4096
#define POS 205                 // max(1, round(0.8 * 256))

typedef float f32x4 __attribute__((ext_vector_type(4)));

// ---------------------------------------------------------------------------
// Kernel 1 (R8-proven config): fused copy + mean, 2 rows per block,
// 4096 blocks. Plain caching loads; NT stores (keep out from evicting x in
// LLC — measured FETCH 67MB < 134MB). 8 x 16B loads in flight per thread;
// single reduction barrier at the end (no inter-pair serialization).
// ---------------------------------------------------------------------------
__global__ void mean_copy_kernel(const float* __restrict__ x,
                                 float* __restrict__ out,
                                 float* __restrict__ y) {
    const int r0 = blockIdx.x * 2;                   // rows r0, r0+1
    const int t = threadIdx.x;                       // 0 .. 255
    const f32x4* x0 = (const f32x4*)(x + (size_t)r0 * HWSZ);
    f32x4* o0 = (f32x4*)(out + (size_t)r0 * HWSZ);

    f32x4 v0[4], v1[4];
#pragma unroll
    for (int i = 0; i < 4; ++i) v0[i] = x0[t + i * 256];
#pragma unroll
    for (int i = 0; i < 4; ++i) v1[i] = x0[1024 + t + i * 256];

    float s0 = 0.f, s1 = 0.f;
#pragma unroll
    for (int i = 0; i < 4; ++i) {
        __builtin_nontemporal_store(v0[i], &o0[t + i * 256]);
        s0 += v0[i].x + v0[i].y + v0[i].z + v0[i].w;
    }
#pragma unroll
    for (int i = 0; i < 4; ++i) {
        __builtin_nontemporal_store(v1[i], &o0[1024 + t + i * 256]);
        s1 += v1[i].x + v1[i].y + v1[i].z + v1[i].w;
    }

#pragma unroll
    for (int off = 32; off > 0; off >>= 1) {
        s0 += __shfl_down(s0, off, 64);
        s1 += __shfl_down(s1, off, 64);
    }
    __shared__ float red[8];
    const int wave = t >> 6;
    if ((t & 63) == 0) { red[wave] = s0; red[wave + 4] = s1; }
    __syncthreads();
    if (t == 0) {
        y[r0]     = (red[0] + red[1] + red[2] + red[3]) * (1.0f / (float)HWSZ);
        y[r0 + 1] = (red[4] + red[5] + red[6] + red[7]) * (1.0f / (float)HWSZ);
    }
}

// ---------------------------------------------------------------------------
// Kernel 2 (R8-proven): fused SE + zero, 2048 blocks = 64 per batch.
// Ballot-based rank count for the block's own 4 channels only, then zero
// masked channels {k, k+64, k+128, k+192} of batch b with NT writes.
//   keep(c) = (#{j : s[j] < s[c]} <= POS-1)  ==  (s[c] <= sorted(s)[POS-1])
// ---------------------------------------------------------------------------
__global__ void se_zero_kernel(const float* __restrict__ y,
                               const float* __restrict__ W1,
                               const float* __restrict__ W2,
                               float* __restrict__ out) {
    const int b = blockIdx.x >> 6;                   // batch 0..31
    const int k = blockIdx.x & 63;                   // sub-block 0..63
    const int t = threadIdx.x;                       // 0 .. 255
    __shared__ float ys[CC];
    __shared__ float hs[RR];
    __shared__ float ss[CC];
    __shared__ int cntred[4][4];                     // [cc][wave]
    __shared__ int keepb[4];

    ys[t] = y[b * CC + t];
    __syncthreads();

    {   // h[r]: r = t>>4 (0..15), 16-lane group splits the 256-dot
        const int r = t >> 4;
        const int p = t & 15;
        float acc = 0.f;
#pragma unroll
        for (int j = 0; j < 16; ++j)
            acc += ys[p * 16 + j] * W1[r * CC + p * 16 + j];
#pragma unroll
        for (int off = 8; off > 0; off >>= 1) acc += __shfl_xor(acc, off, 16);
        if (p == 0) hs[r] = fmaxf(acc, 0.f);
    }
    __syncthreads();

    float acc = 0.f;
#pragma unroll
    for (int r = 0; r < RR; ++r) acc += hs[r] * W2[t * RR + r];
    const float s = 1.0f / (1.0f + expf(-acc));
    ss[t] = s;
    __syncthreads();

    // rank counts for this block's 4 channels only, via wave ballots
    const int wave = t >> 6;
#pragma unroll
    for (int cc = 0; cc < 4; ++cc) {
        const float sc = ss[k + cc * 64];
        unsigned long long m = __ballot(s < sc);     // lanes j with s[j] < s[c]
        if ((t & 63) == 0) cntred[cc][wave] = __popcll(m);
    }
    __syncthreads();
    if (t < 4)
        keepb[t] = (cntred[t][0] + cntred[t][1] + cntred[t][2] + cntred[t][3]) <= POS - 1;
    __syncthreads();

    // zero phase: channels {k, k+64, k+128, k+192} of batch b
    f32x4 z = {0.f, 0.f, 0.f, 0.f};
#pragma unroll
    for (int cc = 0; cc < 4; ++cc) {
        if (keepb[cc]) continue;
        const int c = k + cc * 64;
        f32x4* orow = (f32x4*)(out + ((size_t)b * CC + c) * HWSZ);
#pragma unroll
        for (int i = 0; i < 4; ++i)
            __builtin_nontemporal_store(z, &orow[t + i * 256]);
    }
}

extern "C" void kernel_launch(void* const* d_in, const int* in_sizes, int n_in,
                              void* d_out, int out_size, void* d_ws, size_t ws_size,
                              hipStream_t stream) {
    const float* x  = (const float*)d_in[0];
    const float* W1 = (const float*)d_in[1];
    const float* W2 = (const float*)d_in[2];
    float* out = (float*)d_out;

    float* y = (float*)d_ws;                    // B*C floats

    mean_copy_kernel<<<BB * CC / 2, 256, 0, stream>>>(x, out, y);
    se_zero_kernel<<<BB * 64, 256, 0, stream>>>(y, W1, W2, out);
}